// Round 21
// baseline (127.571 us; speedup 1.0000x reference)
//
#include <hip/hip_runtime.h>
#include <hip/hip_bf16.h>

#define NN 50000
#define CIN 128
#define HH 4
#define DD 32
#define HD 128
#define EE 800000
#define NEG 0.2f

typedef unsigned short ushortT;
typedef unsigned int uintT;
typedef __attribute__((ext_vector_type(8))) short bf16x8;
typedef __attribute__((ext_vector_type(4))) float f32x4;
typedef unsigned int uint4v __attribute__((ext_vector_type(4)));

// ---------------------------------------------------------------------------
// ws layout (units of 4B):
//   CNT_OFF  = 16       : per-node in-degree (excl self) (NN ints) [zeroed by wprep]
//   ROW_OFF  = 50016    : CSR row offsets, block-local (NN+1 ints)
//   RANK_OFF = 100032   : per-edge rank within dst segment (EE ints)
//   ESRC_OFF = 900048   : dst-sorted src indices (EE ints)
//   BTOT_OFF = 1700064  : scan block totals (RAW, 64 ints)
//   WBF_OFF  = 1700128  : W bf16 [256][128] (16384 float-slots)
//   XPH_OFF  = 1716512  : INTERLEAVED bf16 rows: word[n*128 + l*2 + part]
//                         = bf16 pair (dims 2l,2l+1) of part∈{xl,xr} (3.2M words)
// ---------------------------------------------------------------------------
#define CNT_OFF  16
#define ROW_OFF  50016
#define RANK_OFF 100032
#define ESRC_OFF 900048
#define BTOT_OFF 1700064
#define WBF_OFF  1700128
#define XPH_OFF  1716512
#define SCAN_NB  49          // ceil((NN+1)/1024)
#define GEMM_NB  1563        // (NN+31)/32
#define HIST_NB  782         // ceil(EE / (256*4))
#define TOT_NB   2346        // 3 * HIST_NB

__device__ __forceinline__ ushortT f2bf(float f) {
    uintT u = __float_as_uint(f);
    u = (u + 0x7fff + ((u >> 16) & 1)) >> 16;   // RNE
    return (ushortT)u;
}
__device__ __forceinline__ float bflo(uintT u) { return __uint_as_float(u << 16); }
__device__ __forceinline__ float bfhi(uintT u) { return __uint_as_float(u & 0xffff0000u); }

// convert Wl|Wr to bf16 AND zero cnt (replaces the memset dispatch)
__global__ __launch_bounds__(256) void wprep_kernel(
    const float* __restrict__ Wl, const float* __restrict__ Wr,
    ushortT* __restrict__ wbf, int* __restrict__ cnt)
{
    const int i = blockIdx.x * 256 + threadIdx.x;   // 4096 threads
    const float* src = (i < 2048) ? Wl : Wr;
    const int off = (i < 2048) ? i : i - 2048;
    const float4 v0 = *(const float4*)(src + (size_t)off * 8);
    const float4 v1 = *(const float4*)(src + (size_t)off * 8 + 4);
    bf16x8 o;
    o[0] = f2bf(v0.x); o[1] = f2bf(v0.y); o[2] = f2bf(v0.z); o[3] = f2bf(v0.w);
    o[4] = f2bf(v1.x); o[5] = f2bf(v1.y); o[6] = f2bf(v1.z); o[7] = f2bf(v1.w);
    *(bf16x8*)(wbf + ((i < 2048) ? 0 : 16384) + (size_t)off * 8) = o;
    for (int j = i; j < NN; j += 4096) cnt[j] = 0;
}

// ---------------------------------------------------------------------------
// COMBO, INTERLEAVED roles: blockIdx%3 ∈ {0,1} -> gemm (gid=(b/3)*2+b%3),
// blockIdx%3 == 2 -> hist (4 edges/thread, rank = atomic return value).
// gemm epilogue writes the word-interleaved xph2 layout.
// ---------------------------------------------------------------------------
__global__ __launch_bounds__(256) void combo_kernel(
    const float* __restrict__ x, const ushortT* __restrict__ wbf,
    uintT* __restrict__ xph2, const int* __restrict__ ei_raw,
    int* __restrict__ cnt, int* __restrict__ rank)
{
    __shared__ ushortT smem[9216];        // 18.4 KB: xa[32][136] then tl[4][32][72]
    __shared__ int sflag;
    const int t = threadIdx.x;
    const int role = blockIdx.x % 3;

    if (role == 2) {
        // ---- histogram + rank path (4 edges/thread) ----
        if (t < 64) {
            const int w = ei_raw[2 * t + 1];
            const unsigned long long b = __ballot(w != 0);
            if (t == 0) sflag = (b == 0ULL) ? 1 : 0;
        }
        __syncthreads();
        const int f = sflag;
        const int t0 = (blockIdx.x / 3) * 256 + t;
        const int stride = HIST_NB * 256;
        #pragma unroll
        for (int k = 0; k < 4; ++k) {
            const int e = t0 + k * stride;
            if (e < EE) {
                const int d = f ? ei_raw[2 * (EE + e)] : ei_raw[EE + e];
                rank[e] = atomicAdd(&cnt[d], 1);
            }
        }
        return;
    }

    // ---- gemm path ----
    const int gid = (blockIdx.x / 3) * 2 + role;
    if (gid >= GEMM_NB) return;           // pad block
    ushortT (*xa)[136] = (ushortT(*)[136])smem;          // 4352 ushorts
    ushortT (*tl)[32][72] = (ushortT(*)[32][72])smem;    // 9216 ushorts (aliased)
    const int row0 = gid * 32;

    {   // stage + convert 32 rows of x
        const int r = t >> 3, seg = t & 7;
        const int gr = row0 + r;
        const int gr_c = gr < NN ? gr : NN - 1;
        const float* src = x + (size_t)gr_c * CIN + seg * 16;
        const float4 v0 = *(const float4*)(src);
        const float4 v1 = *(const float4*)(src + 4);
        const float4 v2 = *(const float4*)(src + 8);
        const float4 v3 = *(const float4*)(src + 12);
        bf16x8 o0, o1;
        o0[0] = f2bf(v0.x); o0[1] = f2bf(v0.y); o0[2] = f2bf(v0.z); o0[3] = f2bf(v0.w);
        o0[4] = f2bf(v1.x); o0[5] = f2bf(v1.y); o0[6] = f2bf(v1.z); o0[7] = f2bf(v1.w);
        o1[0] = f2bf(v2.x); o1[1] = f2bf(v2.y); o1[2] = f2bf(v2.z); o1[3] = f2bf(v2.w);
        o1[4] = f2bf(v3.x); o1[5] = f2bf(v3.y); o1[6] = f2bf(v3.z); o1[7] = f2bf(v3.w);
        *(bf16x8*)(&xa[r][seg * 16]) = o0;
        *(bf16x8*)(&xa[r][seg * 16 + 8]) = o1;
    }
    __syncthreads();

    const int w = t >> 6, l = t & 63;
    const int part = w >> 1, ch = w & 1;
    const int rowlo = l & 15, kb = (l >> 4) * 8;

    bf16x8 a[2][4];
    #pragma unroll
    for (int rg = 0; rg < 2; ++rg)
        #pragma unroll
        for (int ks = 0; ks < 4; ++ks)
            a[rg][ks] = *(const bf16x8*)(&xa[rg * 16 + rowlo][ks * 32 + kb]);
    __syncthreads();    // all xa reads done before tl overwrites the buffer

    f32x4 acc[2][4] = {};
    const ushortT* wbase = wbf + (size_t)(part * 128 + ch * 64 + rowlo) * 128 + kb;
    #pragma unroll
    for (int ks = 0; ks < 4; ++ks) {
        #pragma unroll
        for (int ct = 0; ct < 4; ++ct) {
            const bf16x8 b = *(const bf16x8*)(wbase + (size_t)ct * 16 * 128 + ks * 32);
            acc[0][ct] = __builtin_amdgcn_mfma_f32_16x16x32_bf16(a[0][ks], b, acc[0][ct], 0, 0, 0);
            acc[1][ct] = __builtin_amdgcn_mfma_f32_16x16x32_bf16(a[1][ks], b, acc[1][ct], 0, 0, 0);
        }
    }

    #pragma unroll
    for (int rg = 0; rg < 2; ++rg)
        #pragma unroll
        for (int ct = 0; ct < 4; ++ct)
            #pragma unroll
            for (int j = 0; j < 4; ++j)
                tl[w][rg * 16 + (l >> 4) * 4 + j][ct * 16 + rowlo] = f2bf(acc[rg][ct][j]);
    __syncthreads();

    // cooperative store, interleaved layout: uint4 = words {l0p0, l0p1, l1p0, l1p1}
    // for lane pair l0=2*i4, l1=2*i4+1; part-local ushort col c0 = 4*i4.
    // part-local col c -> tl[part*2 + (c>>6)][r][c&63].
    #pragma unroll
    for (int c = 0; c < 4; ++c) {
        const int cid = c * 256 + t;      // 0..1023
        const int r = cid >> 5;           // 0..31
        const int i4 = cid & 31;          // uint4 index in row
        const int c0 = i4 * 4;            // 0..124
        const int gr = row0 + r;
        if (gr < NN) {
            const int w0 = c0 >> 6, o0 = c0 & 63;
            const int w2 = (c0 + 2) >> 6, o2 = (c0 + 2) & 63;
            uint4v o;
            o.x = *(const uintT*)(&tl[w0][r][o0]);          // xl dims c0,c0+1
            o.y = *(const uintT*)(&tl[2 + w0][r][o0]);      // xr dims c0,c0+1
            o.z = *(const uintT*)(&tl[w2][r][o2]);          // xl dims c0+2,c0+3
            o.w = *(const uintT*)(&tl[2 + w2][r][o2]);      // xr dims c0+2,c0+3
            *(uint4v*)(xph2 + (size_t)gr * 128 + i4 * 4) = o;
        }
    }
}

// ---------------------------------------------------------------------------
// scan1: block-local exclusive scan of cnt; btot[b] = RAW block total
// ---------------------------------------------------------------------------
__global__ __launch_bounds__(1024) void scan1_kernel(
    const int* __restrict__ cnt, int* __restrict__ row, int* __restrict__ btot)
{
    __shared__ int wtot[16];
    const int t = threadIdx.x, lane = t & 63, wv = t >> 6;
    const int i = blockIdx.x * 1024 + t;
    const int v = (i < NN) ? cnt[i] : 0;
    int acc = v;
    #pragma unroll
    for (int off = 1; off < 64; off <<= 1) {
        const int u = __shfl_up(acc, off, 64);
        if (lane >= off) acc += u;
    }
    if (lane == 63) wtot[wv] = acc;
    __syncthreads();
    if (wv == 0 && lane < 16) {
        const int wvv = wtot[lane];
        int wacc = wvv;
        #pragma unroll
        for (int off = 1; off < 16; off <<= 1) {
            const int u = __shfl_up(wacc, off, 64);
            if (lane >= off) wacc += u;
        }
        wtot[lane] = wacc - wvv;            // exclusive wave offset
    }
    __syncthreads();
    const int ex = wtot[wv] + acc - v;      // block-local exclusive prefix
    if (i <= NN) row[i] = ex;
    if (t == 1023) btot[blockIdx.x] = ex + v;
}

// atomic-free scatter, 4 edges/thread; btot prefix built in LDS per block
__global__ __launch_bounds__(256) void scatter_kernel(
    const int* __restrict__ ei_raw, const int* __restrict__ row,
    const int* __restrict__ btot, const int* __restrict__ rank,
    int* __restrict__ esrc)
{
    __shared__ int sflag;
    __shared__ int pref[64];
    const int t = threadIdx.x;
    if (t < 64) {
        const int w = ei_raw[2 * t + 1];
        const unsigned long long b = __ballot(w != 0);
        if (t == 0) sflag = (b == 0ULL) ? 1 : 0;
        // exclusive prefix of raw btot (49 entries) in-wave
        const int v = (t < SCAN_NB) ? btot[t] : 0;
        int acc = v;
        #pragma unroll
        for (int off = 1; off < 64; off <<= 1) {
            const int u = __shfl_up(acc, off, 64);
            if (t >= off) acc += u;
        }
        pref[t] = acc - v;
    }
    __syncthreads();
    const int f = sflag;
    const int t0 = blockIdx.x * 256 + t;
    const int stride = gridDim.x * 256;
    #pragma unroll
    for (int k = 0; k < 4; ++k) {
        const int e = t0 + k * stride;
        if (e < EE) {
            int s, d;
            if (f) { s = ei_raw[2 * e]; d = ei_raw[2 * (EE + e)]; }
            else   { s = ei_raw[e];     d = ei_raw[EE + e]; }
            esrc[row[d] + pref[d >> 10] + rank[e]] = s;
        }
    }
}

// ---------------------------------------------------------------------------
// Fused per-node GATv2: 128-thread blocks (2 nodes); interleaved xph2 ->
// ONE dwordx2 gather per edge (was two dword gathers). Unrolled 8.
// ---------------------------------------------------------------------------
#define SCORE_OF(ulv, cv)                                                 \
    {                                                                     \
        float vx = bflo(ulv) + rnx, vy = bfhi(ulv) + rny;                 \
        vx = vx > 0.f ? vx : NEG * vx;                                    \
        vy = vy > 0.f ? vy : NEG * vy;                                    \
        cv = vx * a2.x + vy * a2.y;                                       \
    }
#define RED16(cv)                                                         \
    cv += __shfl_xor(cv, 1); cv += __shfl_xor(cv, 2);                     \
    cv += __shfl_xor(cv, 4); cv += __shfl_xor(cv, 8);

#define GROUP4(i0, i1, i2, i3)                                            \
    {                                                                     \
        float c0, c1, c2, c3;                                             \
        SCORE_OF(v[i0].x, c0) SCORE_OF(v[i1].x, c1)                       \
        SCORE_OF(v[i2].x, c2) SCORE_OF(v[i3].x, c3)                       \
        c0 += __shfl_xor(c0, 1); c1 += __shfl_xor(c1, 1);                 \
        c2 += __shfl_xor(c2, 1); c3 += __shfl_xor(c3, 1);                 \
        c0 += __shfl_xor(c0, 2); c1 += __shfl_xor(c1, 2);                 \
        c2 += __shfl_xor(c2, 2); c3 += __shfl_xor(c3, 2);                 \
        c0 += __shfl_xor(c0, 4); c1 += __shfl_xor(c1, 4);                 \
        c2 += __shfl_xor(c2, 4); c3 += __shfl_xor(c3, 4);                 \
        c0 += __shfl_xor(c0, 8); c1 += __shfl_xor(c1, 8);                 \
        c2 += __shfl_xor(c2, 8); c3 += __shfl_xor(c3, 8);                 \
        const float e0 = __expf(c0), e1 = __expf(c1);                     \
        const float e2 = __expf(c2), e3 = __expf(c3);                     \
        den += (e0 + e1) + (e2 + e3);                                     \
        ax = fmaf(e0, bflo(v[i0].y), ax); ay = fmaf(e0, bfhi(v[i0].y), ay); \
        ax = fmaf(e1, bflo(v[i1].y), ax); ay = fmaf(e1, bfhi(v[i1].y), ay); \
        ax = fmaf(e2, bflo(v[i2].y), ax); ay = fmaf(e2, bfhi(v[i2].y), ay); \
        ax = fmaf(e3, bflo(v[i3].y), ax); ay = fmaf(e3, bfhi(v[i3].y), ay); \
    }

__global__ __launch_bounds__(128) void gat_node_kernel(
    const int* __restrict__ row, const int* __restrict__ btot,
    const int* __restrict__ esrc, const uintT* __restrict__ xph2,
    const float* __restrict__ att, const float* __restrict__ bias,
    float* __restrict__ out)
{
    const int lane = threadIdx.x & 63;
    const int h = lane >> 4, dd = lane & 15;
    const int n = blockIdx.x * 2 + (threadIdx.x >> 6);
    if (n >= NN) return;

    // wave-inline exclusive prefix of raw btot at chunk c1 = n>>10
    const int c1 = n >> 10;
    int pv = (lane < c1) ? btot[lane] : 0;
    #pragma unroll
    for (int off = 1; off < 64; off <<= 1) pv += __shfl_xor(pv, off);
    const int c2 = (n + 1) >> 10;
    const int pre2 = pv + ((c2 > c1) ? btot[c1] : 0);

    const float2 a2 = *(const float2*)(att + h * DD + dd * 2);
    const uint2 vn = *(const uint2*)(xph2 + (size_t)n * 128 + lane * 2);
    const uintT uln = vn.x, urn = vn.y;
    const float rnx = bflo(urn), rny = bfhi(urn);

    // self-loop first
    float den, ax, ay;
    {
        float c;
        SCORE_OF(uln, c)
        RED16(c)
        const float pe = __expf(c);
        den = pe;
        ax = pe * bflo(urn);
        ay = pe * bfhi(urn);
    }

    const int p0 = row[n] + pv;
    const int p1 = row[n + 1] + pre2;
    int p = p0;

    for (; p + 8 <= p1; p += 8) {
        int s[8];
        #pragma unroll
        for (int j = 0; j < 8; ++j) s[j] = esrc[p + j];
        uint2 v[8];
        #pragma unroll
        for (int j = 0; j < 8; ++j)
            v[j] = *(const uint2*)(xph2 + (size_t)s[j] * 128 + lane * 2);
        GROUP4(0, 1, 2, 3) GROUP4(4, 5, 6, 7)
    }
    for (; p + 4 <= p1; p += 4) {
        int s[4];
        #pragma unroll
        for (int j = 0; j < 4; ++j) s[j] = esrc[p + j];
        uint2 v[4];
        #pragma unroll
        for (int j = 0; j < 4; ++j)
            v[j] = *(const uint2*)(xph2 + (size_t)s[j] * 128 + lane * 2);
        GROUP4(0, 1, 2, 3)
    }
    for (; p < p1; ++p) {
        const int s = esrc[p];
        const uint2 vv = *(const uint2*)(xph2 + (size_t)s * 128 + lane * 2);
        float c;
        SCORE_OF(vv.x, c)
        RED16(c)
        const float pe = __expf(c);
        den += pe;
        ax = fmaf(pe, bflo(vv.y), ax);
        ay = fmaf(pe, bfhi(vv.y), ay);
    }

    const float inv = 1.f / fmaxf(den, 1e-16f);
    ax *= inv; ay *= inv;
    ax += __shfl_xor(ax, 16); ay += __shfl_xor(ay, 16);
    ax += __shfl_xor(ax, 32); ay += __shfl_xor(ay, 32);
    if (h == 0) {
        float2 o;
        o.x = ax * 0.25f + bias[dd * 2];
        o.y = ay * 0.25f + bias[dd * 2 + 1];
        *(float2*)(out + (size_t)n * DD + dd * 2) = o;
    }
}

extern "C" void kernel_launch(void* const* d_in, const int* in_sizes, int n_in,
                              void* d_out, int out_size, void* d_ws, size_t ws_size,
                              hipStream_t stream)
{
    const float* x    = (const float*)d_in[0];
    const int*   ei   = (const int*)d_in[1];
    const float* Wl   = (const float*)d_in[2];
    const float* Wr   = (const float*)d_in[3];
    const float* att  = (const float*)d_in[4];
    const float* bias = (const float*)d_in[5];
    float* out = (float*)d_out;

    float*   ws   = (float*)d_ws;
    int*     cnt  = (int*)(ws + CNT_OFF);
    int*     row  = (int*)(ws + ROW_OFF);
    int*     rank = (int*)(ws + RANK_OFF);
    int*     esrc = (int*)(ws + ESRC_OFF);
    int*     btot = (int*)(ws + BTOT_OFF);
    ushortT* wbf  = (ushortT*)(ws + WBF_OFF);
    uintT*   xph2 = (uintT*)(ws + XPH_OFF);

    hipLaunchKernelGGL(wprep_kernel, dim3(16), dim3(256), 0, stream, Wl, Wr, wbf, cnt);
    hipLaunchKernelGGL(combo_kernel, dim3(TOT_NB), dim3(256), 0, stream,
                       x, wbf, xph2, ei, cnt, rank);
    hipLaunchKernelGGL(scan1_kernel, dim3(SCAN_NB), dim3(1024), 0, stream, cnt, row, btot);
    hipLaunchKernelGGL(scatter_kernel, dim3(HIST_NB), dim3(256), 0, stream,
                       ei, row, btot, rank, esrc);
    hipLaunchKernelGGL(gat_node_kernel, dim3((NN + 1) / 2), dim3(128), 0, stream,
                       row, btot, esrc, xph2, att, bias, out);
}